// Round 1
// baseline (1232.473 us; speedup 1.0000x reference)
//
#include <hip/hip_runtime.h>

#define IGNORE_INDEX (-100)
#define BM 128
#define BN 128
#define BK 32
#define DD 2048

typedef __attribute__((ext_vector_type(8))) short bf16x8;
typedef __attribute__((ext_vector_type(4))) float f32x4;

__device__ __forceinline__ unsigned short f2bf(float f) {
    union { float f; unsigned u; } x; x.f = f;
    unsigned r = x.u + 0x7FFFu + ((x.u >> 16) & 1u);
    return (unsigned short)(r >> 16);
}

__device__ __forceinline__ void gload_lds16(const void* g, void* l) {
    __builtin_amdgcn_global_load_lds(
        (const __attribute__((address_space(1))) void*)g,
        (__attribute__((address_space(3))) void*)l, 16, 0, 0);
}

// ---------------- fp32 -> bf16 conversion (embeddings, full NR x D) --------
__global__ __launch_bounds__(256) void convE_k(const float* __restrict__ in,
                                               unsigned short* __restrict__ out,
                                               size_t nchunks) {
    size_t i = (size_t)blockIdx.x * 256 + threadIdx.x;
    if (i >= nchunks) return;
    const float4* src = (const float4*)(in + i * 8);
    float4 a = src[0], b = src[1];
    ushort4 o0 = { f2bf(a.x), f2bf(a.y), f2bf(a.z), f2bf(a.w) };
    ushort4 o1 = { f2bf(b.x), f2bf(b.y), f2bf(b.z), f2bf(b.w) };
    ushort4* dst = (ushort4*)(out + i * 8);
    dst[0] = o0; dst[1] = o1;
}

// ---------------- fp32 -> bf16 conversion (weight, padded to Vpad) --------
__global__ __launch_bounds__(256) void convW_k(const float* __restrict__ wt,
                                               unsigned short* __restrict__ out,
                                               int V, size_t nchunks) {
    for (size_t i = (size_t)blockIdx.x * 256 + threadIdx.x; i < nchunks;
         i += (size_t)gridDim.x * 256) {
        size_t base = i * 8;
        size_t v = base >> 11;  // / DD
        ushort4 o0 = {0, 0, 0, 0}, o1 = {0, 0, 0, 0};
        if (v < (size_t)V) {
            const float4* src = (const float4*)(wt + base);
            float4 a = src[0], b = src[1];
            o0 = (ushort4){ f2bf(a.x), f2bf(a.y), f2bf(a.z), f2bf(a.w) };
            o1 = (ushort4){ f2bf(b.x), f2bf(b.y), f2bf(b.z), f2bf(b.w) };
        }
        ushort4* dst = (ushort4*)(out + base);
        dst[0] = o0; dst[1] = o1;
    }
}

// ---------------- fused GEMM + online-LSE partials ------------------------
// C[row, col] = dot(E16[row,:], W[col,:]) + bias[col]; per (128-row, 128-col)
// tile emit per-row (max, sumexp) partial into partials[row*NVT + vt].
template <bool BPRE>
__global__ __launch_bounds__(256) void gemm_lse_k(
    const unsigned short* __restrict__ E16,  // [NR][DD] bf16 bits
    const unsigned short* __restrict__ W16,  // [Vpad][DD] bf16 bits (BPRE)
    const float* __restrict__ Wf,            // [V][DD] fp32 (!BPRE)
    const float* __restrict__ bias,          // [V]
    float2* __restrict__ partials,           // [NR][NVT]
    int NMT, int NVT, int V) {
    __shared__ __align__(16) unsigned short As[BM][BK];
    __shared__ __align__(16) unsigned short Bs[BN][BK];
    __shared__ float redM[2][BM];
    __shared__ float redS[2][BM];

    const int t = threadIdx.x;
    const int lane = t & 63;
    const int wave = t >> 6;
    const int wr = wave >> 1, wc = wave & 1;
    const int lo = lane & 15, hi = lane >> 4;

    const int mt = blockIdx.x % NMT;
    const int vt = blockIdx.x / NMT;

    f32x4 acc[4][4];
#pragma unroll
    for (int m = 0; m < 4; ++m)
#pragma unroll
        for (int n = 0; n < 4; ++n) acc[m][n] = (f32x4){0.f, 0.f, 0.f, 0.f};

    // staging chunk mapping: chunk c covers (row = c>>2, k8 = (c&3)*8), 16B each
    const int c0 = t, c1 = t + 256;
    const int ar0 = c0 >> 2, ak0 = (c0 & 3) * 8;
    const int ar1 = c1 >> 2, ak1 = (c1 & 3) * 8;

    const unsigned short* Ag = E16 + (size_t)mt * BM * DD;

    for (int kt = 0; kt < DD; kt += BK) {
        gload_lds16(Ag + (size_t)ar0 * DD + kt + ak0, &As[ar0][ak0]);
        gload_lds16(Ag + (size_t)ar1 * DD + kt + ak1, &As[ar1][ak1]);
        if constexpr (BPRE) {
            const unsigned short* Bg = W16 + (size_t)vt * BN * DD;
            gload_lds16(Bg + (size_t)ar0 * DD + kt + ak0, &Bs[ar0][ak0]);
            gload_lds16(Bg + (size_t)ar1 * DD + kt + ak1, &Bs[ar1][ak1]);
        } else {
#pragma unroll
            for (int j = 0; j < 2; ++j) {
                int row = (j == 0) ? ar0 : ar1;
                int kk = (j == 0) ? ak0 : ak1;
                int v = vt * BN + row;
                ushort4 o0 = {0, 0, 0, 0}, o1 = {0, 0, 0, 0};
                if (v < V) {
                    const float* src = Wf + (size_t)v * DD + kt + kk;
                    float4 a = *(const float4*)src;
                    float4 b = *(const float4*)(src + 4);
                    o0 = (ushort4){ f2bf(a.x), f2bf(a.y), f2bf(a.z), f2bf(a.w) };
                    o1 = (ushort4){ f2bf(b.x), f2bf(b.y), f2bf(b.z), f2bf(b.w) };
                }
                *(ushort4*)&Bs[row][kk] = o0;
                *(ushort4*)&Bs[row][kk + 4] = o1;
            }
        }
        __syncthreads();
        bf16x8 af[4], bfr[4];
#pragma unroll
        for (int m = 0; m < 4; ++m)
            af[m] = *(const bf16x8*)&As[wr * 64 + m * 16 + lo][hi * 8];
#pragma unroll
        for (int n = 0; n < 4; ++n)
            bfr[n] = *(const bf16x8*)&Bs[wc * 64 + n * 16 + lo][hi * 8];
#pragma unroll
        for (int m = 0; m < 4; ++m)
#pragma unroll
            for (int n = 0; n < 4; ++n)
                acc[m][n] = __builtin_amdgcn_mfma_f32_16x16x32_bf16(
                    af[m], bfr[n], acc[m][n], 0, 0, 0);
        __syncthreads();
    }

    // ---- epilogue: bias add + per-row (max, sumexp) over this 128-col tile
    // acc[m][n] reg q: row_in_block = wr*64 + m*16 + hi*4 + q
    //                  col_in_block = wc*64 + n*16 + lo
    float bias_n[4];
    const int colbase = vt * BN + wc * 64 + lo;
#pragma unroll
    for (int n = 0; n < 4; ++n) {
        int col = colbase + n * 16;
        bias_n[n] = (col < V) ? bias[col] : 0.0f;
    }
#pragma unroll
    for (int m = 0; m < 4; ++m) {
#pragma unroll
        for (int q = 0; q < 4; ++q) {
            float l[4];
            float vmax = -1e30f;
#pragma unroll
            for (int n = 0; n < 4; ++n) {
                int col = colbase + n * 16;
                float x = (col < V) ? (acc[m][n][q] + bias_n[n]) : -1e30f;
                l[n] = x;
                vmax = fmaxf(vmax, x);
            }
#pragma unroll
            for (int d = 1; d < 16; d <<= 1)
                vmax = fmaxf(vmax, __shfl_xor(vmax, d));
            float s = 0.f;
#pragma unroll
            for (int n = 0; n < 4; ++n) s += __expf(l[n] - vmax);
#pragma unroll
            for (int d = 1; d < 16; d <<= 1) s += __shfl_xor(s, d);
            if (lo == 0) {
                int r = wr * 64 + m * 16 + hi * 4 + q;
                redM[wc][r] = vmax;
                redS[wc][r] = s;
            }
        }
    }
    __syncthreads();
    if (t < BM) {
        float M0 = redM[0][t], M1 = redM[1][t];
        float S0 = redS[0][t], S1 = redS[1][t];
        float M = fmaxf(M0, M1);
        float S = S0 * __expf(M0 - M) + S1 * __expf(M1 - M);
        size_t row = (size_t)mt * BM + t;
        partials[row * NVT + vt] = make_float2(M, S);
    }
}

// ---------------- fp32 true-logit per row (one wave per row) --------------
__global__ __launch_bounds__(256) void true_logit_k(
    const float* __restrict__ emb, const float* __restrict__ wt,
    const float* __restrict__ bias, const int* __restrict__ labels,
    float* __restrict__ tl, int* __restrict__ validf, int NR, int V, int S) {
    int wid = blockIdx.x * 4 + (threadIdx.x >> 6);
    int lane = threadIdx.x & 63;
    if (wid >= NR) return;
    int b = wid / S, s = wid % S;
    int valid = 0;
    float val = 0.f;
    if (s < S - 1) {
        int y = labels[b * S + s + 1];
        if (y != IGNORE_INDEX) {
            valid = 1;
            int ys = (y >= 0 && y < V) ? y : 0;
            const float4* e4 = (const float4*)(emb + ((size_t)b * S + s) * DD);
            const float4* w4 = (const float4*)(wt + (size_t)ys * DD);
            float sum = 0.f;
            for (int i = lane; i < DD / 4; i += 64) {
                float4 a = e4[i], w = w4[i];
                sum += a.x * w.x + a.y * w.y + a.z * w.z + a.w * w.w;
            }
#pragma unroll
            for (int d = 1; d < 64; d <<= 1) sum += __shfl_xor(sum, d);
            val = sum + bias[ys];
        }
    }
    if (lane == 0) {
        tl[wid] = val;
        validf[wid] = valid;
    }
}

// ---------------- combine partials -> per-row NLL -> global sum -----------
__global__ __launch_bounds__(256) void reduce_rows_k(
    const float2* __restrict__ partials, const float* __restrict__ tl,
    const int* __restrict__ validf, float* __restrict__ accum, int NR,
    int NVT, int S) {
    int wid = blockIdx.x * 4 + (threadIdx.x >> 6);
    int lane = threadIdx.x & 63;
    if (wid >= NR) return;
    int s = wid % S;
    if (s >= S - 1) return;
    if (!validf[wid]) return;
    float M = -1e30f, Sm = 0.f;
    const float2* p = partials + (size_t)wid * NVT;
    for (int v = lane; v < NVT; v += 64) {
        float2 ms = p[v];
        float nM = fmaxf(M, ms.x);
        Sm = Sm * __expf(M - nM) + ms.y * __expf(ms.x - nM);
        M = nM;
    }
#pragma unroll
    for (int d = 1; d < 64; d <<= 1) {
        float oM = __shfl_xor(M, d), oS = __shfl_xor(Sm, d);
        float nM = fmaxf(M, oM);
        Sm = Sm * __expf(M - nM) + oS * __expf(oM - nM);
        M = nM;
    }
    if (lane == 0) {
        float lse = M + __logf(Sm);
        float nll = lse - tl[wid];
        atomicAdd(&accum[0], nll);
        atomicAdd(&accum[1], 1.0f);
    }
}

__global__ void finalize_k(const float* __restrict__ accum,
                           float* __restrict__ out) {
    out[0] = accum[0] / fmaxf(accum[1], 1.0f);
}

extern "C" void kernel_launch(void* const* d_in, const int* in_sizes, int n_in,
                              void* d_out, int out_size, void* d_ws,
                              size_t ws_size, hipStream_t stream) {
    const float* emb = (const float*)d_in[0];
    const float* wt = (const float*)d_in[1];
    const float* bias = (const float*)d_in[2];
    const int* labels = (const int*)d_in[3];

    const int B = 2, S = 2048;
    const int V = in_sizes[2];            // 50257
    const int NR = B * S;                 // 4096 rows (incl. 2 invalid)
    const int NMT = NR / BM;              // 32
    const int NVT = (V + BN - 1) / BN;    // 393
    const int Vpad = NVT * BN;            // 50304

    char* p = (char*)d_ws;
    unsigned short* E16 = (unsigned short*)p;
    p += (size_t)NR * DD * 2;
    float2* partials = (float2*)p;
    p += (size_t)NR * NVT * sizeof(float2);
    float* tl = (float*)p;
    p += (size_t)NR * 4;
    int* validf = (int*)p;
    p += (size_t)NR * 4;
    float* accum = (float*)p;
    p += 256;
    unsigned short* W16 = (unsigned short*)p;
    size_t need_fast = (size_t)(p - (char*)d_ws) + (size_t)Vpad * DD * 2;
    bool fast = ws_size >= need_fast;

    hipMemsetAsync(accum, 0, 8, stream);

    size_t echunks = (size_t)NR * DD / 8;
    convE_k<<<(int)((echunks + 255) / 256), 256, 0, stream>>>(emb, E16, echunks);

    if (fast) {
        size_t wchunks = (size_t)Vpad * DD / 8;
        convW_k<<<8192, 256, 0, stream>>>(wt, W16, V, wchunks);
        gemm_lse_k<true><<<NMT * NVT, 256, 0, stream>>>(E16, W16, nullptr, bias,
                                                        partials, NMT, NVT, V);
    } else {
        gemm_lse_k<false><<<NMT * NVT, 256, 0, stream>>>(E16, nullptr, wt, bias,
                                                         partials, NMT, NVT, V);
    }

    true_logit_k<<<NR / 4, 256, 0, stream>>>(emb, wt, bias, labels, tl, validf,
                                             NR, V, S);
    reduce_rows_k<<<NR / 4, 256, 0, stream>>>(partials, tl, validf, accum, NR,
                                              NVT, S);
    finalize_k<<<1, 1, 0, stream>>>(accum, (float*)d_out);
}

// Round 2
// 1021.763 us; speedup vs baseline: 1.2062x; 1.2062x over previous
//
#include <hip/hip_runtime.h>

#define IGNORE_INDEX (-100)
#define DD 2048
#define BM 256
#define BN 256
#define BK 64
#define NKT 32   // DD/BK
#define NMT 16   // 4096/BM
#define THREADS 512
#define LDS_TOTAL 139264

typedef __attribute__((ext_vector_type(8))) short bf16x8;
typedef __attribute__((ext_vector_type(4))) float f32x4;

__device__ __forceinline__ unsigned short f2bf(float f) {
    union { float f; unsigned u; } x; x.f = f;
    unsigned r = x.u + 0x7FFFu + ((x.u >> 16) & 1u);
    return (unsigned short)(r >> 16);
}

__device__ __forceinline__ void gload_lds16(const void* g, void* l) {
    __builtin_amdgcn_global_load_lds(
        (const __attribute__((address_space(1))) void*)g,
        (__attribute__((address_space(3))) void*)l, 16, 0, 0);
}

// ---------------- fp32 -> bf16 conversion (embeddings) --------------------
__global__ __launch_bounds__(256) void convE_k(const float* __restrict__ in,
                                               unsigned short* __restrict__ out,
                                               size_t nchunks) {
    size_t i = (size_t)blockIdx.x * 256 + threadIdx.x;
    if (i >= nchunks) return;
    const float4* src = (const float4*)(in + i * 8);
    float4 a = src[0], b = src[1];
    ushort4 o0 = { f2bf(a.x), f2bf(a.y), f2bf(a.z), f2bf(a.w) };
    ushort4 o1 = { f2bf(b.x), f2bf(b.y), f2bf(b.z), f2bf(b.w) };
    ushort4* dst = (ushort4*)(out + i * 8);
    dst[0] = o0; dst[1] = o1;
}

// ---------------- fp32 -> bf16 conversion (weight, zero-pad to Vpad) ------
__global__ __launch_bounds__(256) void convW_k(const float* __restrict__ wt,
                                               unsigned short* __restrict__ out,
                                               int V, size_t nchunks) {
    for (size_t i = (size_t)blockIdx.x * 256 + threadIdx.x; i < nchunks;
         i += (size_t)gridDim.x * 256) {
        size_t base = i * 8;
        size_t v = base >> 11;  // / DD
        ushort4 o0 = {0, 0, 0, 0}, o1 = {0, 0, 0, 0};
        if (v < (size_t)V) {
            const float4* src = (const float4*)(wt + base);
            float4 a = src[0], b = src[1];
            o0 = (ushort4){ f2bf(a.x), f2bf(a.y), f2bf(a.z), f2bf(a.w) };
            o1 = (ushort4){ f2bf(b.x), f2bf(b.y), f2bf(b.z), f2bf(b.w) };
        }
        ushort4* dst = (ushort4*)(out + base);
        dst[0] = o0; dst[1] = o1;
    }
}

// ---------------- 256x256 8-phase GEMM + online-LSE epilogue --------------
// LDS map (dynamic): bufA0 @0 (32K), bufB0 @32768, bufA1 @65536, bufB1 @98304,
//                    redM @131072 (4K), redS @135168 (4K). Total 139264.
// Swizzle (T2): lds byte for (row R, col-byte cb) = R*128 + (cb ^ ((R&7)<<4)).
// gload_lds writes linearly, so the SAME XOR is pre-applied to the global
// source column (rule #21: involution on both sides).
// Stage slot ledger (phases 0..7 of iter i; buf0=T(2i), buf1=T(2i+1)):
//   reads of a K-tile group at phases P..P+3: A @P(mh0),P+2(mh1); B @P(nh0),P+1(nh1)
//   ph0: T(2i+1).A0 -> buf1.A  (buf1.A last read prev ph6)   ph1: T(2i+1).A1
//   ph2: T(2i+2).B0 -> buf0.B  (buf0.B last read ph1)        ph3: T(2i+2).B1 + vmcnt(4)
//   ph4: T(2i+2).A0 -> buf0.A  (buf0.A last read ph2)        ph5: T(2i+2).A1
//   ph6: T(2i+3).B0 -> buf1.B  (buf1.B last read ph5)        ph7: T(2i+3).B1 + vmcnt(4)
// vmcnt(4) at ph3 leaves only T(2i+2).B0,B1 (2 half-tiles = 4 loads) in
// flight => T(2i+1) fully landed before ph4's ds_reads. Symmetric at ph7.

#define LDA4(B, MH)                                                         \
    do {                                                                    \
        _Pragma("unroll") for (int mm = 0; mm < 4; ++mm)                    \
        _Pragma("unroll") for (int kk = 0; kk < 2; ++kk)                    \
            a[mm][kk] = ldA(B, MH, mm, kk);                                 \
    } while (0)
#define LDB4(B, NH, ARR)                                                    \
    do {                                                                    \
        _Pragma("unroll") for (int nn = 0; nn < 2; ++nn)                    \
        _Pragma("unroll") for (int kk = 0; kk < 2; ++kk)                    \
            ARR[nn][kk] = ldB(B, NH, nn, kk);                               \
    } while (0)
#define MFMAQ(MH, NH, ARR)                                                  \
    do {                                                                    \
        __builtin_amdgcn_s_setprio(1);                                      \
        _Pragma("unroll") for (int mm = 0; mm < 4; ++mm)                    \
        _Pragma("unroll") for (int nn = 0; nn < 2; ++nn)                    \
        _Pragma("unroll") for (int kk = 0; kk < 2; ++kk)                    \
            acc[(MH)*4 + mm][(NH)*2 + nn] =                                 \
                __builtin_amdgcn_mfma_f32_16x16x32_bf16(                    \
                    a[mm][kk], ARR[nn][kk], acc[(MH)*4 + mm][(NH)*2 + nn],  \
                    0, 0, 0);                                               \
        __builtin_amdgcn_s_setprio(0);                                      \
    } while (0)
#define BAR()                                                               \
    do {                                                                    \
        __builtin_amdgcn_sched_barrier(0);                                  \
        __builtin_amdgcn_s_barrier();                                       \
        __builtin_amdgcn_sched_barrier(0);                                  \
    } while (0)
#define WAITV(N) asm volatile("s_waitcnt vmcnt(" #N ")" ::: "memory")

__global__ __launch_bounds__(THREADS, 2) void gemm_lse256_k(
    const unsigned short* __restrict__ E16,   // [4096][DD] bf16 bits
    const unsigned short* __restrict__ W16,   // [Vpad][DD] bf16 bits
    const float* __restrict__ bias,           // [V]
    float2* __restrict__ partials,            // [NR][NVT]
    int NVT, int V) {
    extern __shared__ char smem[];
    const int t = threadIdx.x;
    const int lane = t & 63;
    const int wave = t >> 6;
    const int wr = wave >> 2;   // 0..1
    const int wc = wave & 3;    // 0..3
    const int lo = lane & 15;
    const int hi = lane >> 4;

    // bijective XCD swizzle (m204)
    const int nwg = NMT * NVT;
    const int xcd = blockIdx.x & 7;
    const int idx = blockIdx.x >> 3;
    const int q8 = nwg >> 3, r8 = nwg & 7;
    const int swz = (xcd < r8 ? xcd * (q8 + 1) : r8 * (q8 + 1) + (xcd - r8) * q8) + idx;
    const int mt = swz & (NMT - 1);
    const int vt = swz >> 4;

    const unsigned short* Ag = E16 + (size_t)mt * BM * DD;
    const unsigned short* Bg = W16 + (size_t)vt * BN * DD;

    char* bufA[2] = { smem, smem + 65536 };
    char* bufB[2] = { smem + 32768, smem + 98304 };

    f32x4 acc[8][4];
#pragma unroll
    for (int m = 0; m < 8; ++m)
#pragma unroll
        for (int n = 0; n < 4; ++n) acc[m][n] = (f32x4){0.f, 0.f, 0.f, 0.f};
    bf16x8 a[4][2], b0[2][2], b1[2][2];

    const int srow = lane >> 3;
    const int scb = (lane & 7) * 16;

    auto stageA = [&](int b, int h, int kt) {
#pragma unroll
        for (int j = 0; j < 2; ++j) {
            int c = wave * 2 + j;
            int row = c * 8 + srow;
            int cbs = scb ^ ((row & 7) << 4);
            const unsigned short* src = Ag + (size_t)(h * 128 + row) * DD +
                                        (size_t)(kt & (NKT - 1)) * BK + (cbs >> 1);
            gload_lds16(src, bufA[b] + h * 16384 + c * 1024);
        }
    };
    auto stageB = [&](int b, int h, int kt) {
#pragma unroll
        for (int j = 0; j < 2; ++j) {
            int c = wave * 2 + j;
            int row = c * 8 + srow;
            int cbs = scb ^ ((row & 7) << 4);
            const unsigned short* src = Bg + (size_t)(h * 128 + row) * DD +
                                        (size_t)(kt & (NKT - 1)) * BK + (cbs >> 1);
            gload_lds16(src, bufB[b] + h * 16384 + c * 1024);
        }
    };
    auto ldA = [&](int b, int mh, int mm, int kk) -> bf16x8 {
        int R = wr * 128 + mh * 64 + mm * 16 + lo;
        int cb = kk * 64 + hi * 16;
        return *(const bf16x8*)(bufA[b] + R * 128 + (cb ^ ((R & 7) << 4)));
    };
    auto ldB = [&](int b, int nh, int nn, int kk) -> bf16x8 {
        int R = wc * 64 + nh * 32 + nn * 16 + lo;
        int cb = kk * 64 + hi * 16;
        return *(const bf16x8*)(bufB[b] + R * 128 + (cb ^ ((R & 7) << 4)));
    };

    // prologue: T0 (all 4 halves) -> buf0; T1.B0,B1 -> buf1
    stageA(0, 0, 0); stageA(0, 1, 0);
    stageB(0, 0, 0); stageB(0, 1, 0);
    stageB(1, 0, 1); stageB(1, 1, 1);
    WAITV(4);   // T0 fully landed; T1.B0,B1 in flight
    BAR();

    for (int i = 0; i < NKT / 2; ++i) {
        const int k0 = 2 * i;
        // ph0
        LDA4(0, 0); LDB4(0, 0, b0);
        stageA(1, 0, k0 + 1);
        BAR(); MFMAQ(0, 0, b0); BAR();
        // ph1
        LDB4(0, 1, b1);
        stageA(1, 1, k0 + 1);
        BAR(); MFMAQ(0, 1, b1); BAR();
        // ph2
        LDA4(0, 1);
        stageB(0, 0, k0 + 2);
        BAR(); MFMAQ(1, 1, b1); BAR();
        // ph3
        stageB(0, 1, k0 + 2);
        WAITV(4);
        BAR(); MFMAQ(1, 0, b0); BAR();
        // ph4
        LDA4(1, 0); LDB4(1, 0, b0);
        stageA(0, 0, k0 + 2);
        BAR(); MFMAQ(0, 0, b0); BAR();
        // ph5
        LDB4(1, 1, b1);
        stageA(0, 1, k0 + 2);
        BAR(); MFMAQ(0, 1, b1); BAR();
        // ph6
        LDA4(1, 1);
        stageB(1, 0, k0 + 3);
        BAR(); MFMAQ(1, 1, b1); BAR();
        // ph7
        stageB(1, 1, k0 + 3);
        WAITV(4);
        BAR(); MFMAQ(1, 0, b0); BAR();
    }

    WAITV(0);
    __syncthreads();

    // ---- epilogue: bias add + per-row (max, sumexp) over this 256-col tile
    float* redM = (float*)(smem + 131072);
    float* redS = (float*)(smem + 135168);
    const int colbase = vt * BN + wc * 64 + lo;
    float bias_n[4];
#pragma unroll
    for (int n = 0; n < 4; ++n) {
        int col = colbase + n * 16;
        bias_n[n] = (col < V) ? bias[col] : 0.0f;
    }
#pragma unroll
    for (int m = 0; m < 8; ++m) {
#pragma unroll
        for (int qq = 0; qq < 4; ++qq) {
            float l[4];
            float vmax = -1e30f;
#pragma unroll
            for (int n = 0; n < 4; ++n) {
                int col = colbase + n * 16;
                float x = (col < V) ? (acc[m][n][qq] + bias_n[n]) : -1e30f;
                l[n] = x;
                vmax = fmaxf(vmax, x);
            }
#pragma unroll
            for (int d = 1; d < 16; d <<= 1) vmax = fmaxf(vmax, __shfl_xor(vmax, d));
            float s = 0.f;
#pragma unroll
            for (int n = 0; n < 4; ++n) s += __expf(l[n] - vmax);
#pragma unroll
            for (int d = 1; d < 16; d <<= 1) s += __shfl_xor(s, d);
            if (lo == 0) {
                int R = wr * 128 + m * 16 + hi * 4 + qq;
                redM[wc * 256 + R] = vmax;
                redS[wc * 256 + R] = s;
            }
        }
    }
    __syncthreads();
    if (t < 256) {
        float M = redM[t], S = redS[t];
#pragma unroll
        for (int w2 = 1; w2 < 4; ++w2) {
            float m2 = redM[w2 * 256 + t], s2 = redS[w2 * 256 + t];
            float nM = fmaxf(M, m2);
            S = S * __expf(M - nM) + s2 * __expf(m2 - nM);
            M = nM;
        }
        size_t row = (size_t)mt * BM + t;
        partials[row * (size_t)NVT + vt] = make_float2(M, S);
    }
}

// ---------------- fp32 true-logit per row (one wave per row) --------------
__global__ __launch_bounds__(256) void true_logit_k(
    const float* __restrict__ emb, const float* __restrict__ wt,
    const float* __restrict__ bias, const int* __restrict__ labels,
    float* __restrict__ tl, int* __restrict__ validf, int NR, int V, int S) {
    int wid = blockIdx.x * 4 + (threadIdx.x >> 6);
    int lane = threadIdx.x & 63;
    if (wid >= NR) return;
    int b = wid / S, s = wid % S;
    int valid = 0;
    float val = 0.f;
    if (s < S - 1) {
        int y = labels[b * S + s + 1];
        if (y != IGNORE_INDEX) {
            valid = 1;
            int ys = (y >= 0 && y < V) ? y : 0;
            const float4* e4 = (const float4*)(emb + ((size_t)b * S + s) * DD);
            const float4* w4 = (const float4*)(wt + (size_t)ys * DD);
            float sum = 0.f;
            for (int i = lane; i < DD / 4; i += 64) {
                float4 aa = e4[i], w = w4[i];
                sum += aa.x * w.x + aa.y * w.y + aa.z * w.z + aa.w * w.w;
            }
#pragma unroll
            for (int d = 1; d < 64; d <<= 1) sum += __shfl_xor(sum, d);
            val = sum + bias[ys];
        }
    }
    if (lane == 0) {
        tl[wid] = val;
        validf[wid] = valid;
    }
}

// ---------------- combine partials -> per-row NLL -> global sum -----------
__global__ __launch_bounds__(256) void reduce_rows_k(
    const float2* __restrict__ partials, const float* __restrict__ tl,
    const int* __restrict__ validf, float* __restrict__ accum, int NR,
    int NVT, int S) {
    int wid = blockIdx.x * 4 + (threadIdx.x >> 6);
    int lane = threadIdx.x & 63;
    if (wid >= NR) return;
    int s = wid % S;
    if (s >= S - 1) return;
    if (!validf[wid]) return;
    float M = -1e30f, Sm = 0.f;
    const float2* p = partials + (size_t)wid * NVT;
    for (int v = lane; v < NVT; v += 64) {
        float2 ms = p[v];
        float nM = fmaxf(M, ms.x);
        Sm = Sm * __expf(M - nM) + ms.y * __expf(ms.x - nM);
        M = nM;
    }
#pragma unroll
    for (int d = 1; d < 64; d <<= 1) {
        float oM = __shfl_xor(M, d), oS = __shfl_xor(Sm, d);
        float nM = fmaxf(M, oM);
        Sm = Sm * __expf(M - nM) + oS * __expf(oM - nM);
        M = nM;
    }
    if (lane == 0) {
        float lse = M + __logf(Sm);
        float nll = lse - tl[wid];
        atomicAdd(&accum[0], nll);
        atomicAdd(&accum[1], 1.0f);
    }
}

__global__ void finalize_k(const float* __restrict__ accum,
                           float* __restrict__ out) {
    out[0] = accum[0] / fmaxf(accum[1], 1.0f);
}

extern "C" void kernel_launch(void* const* d_in, const int* in_sizes, int n_in,
                              void* d_out, int out_size, void* d_ws,
                              size_t ws_size, hipStream_t stream) {
    const float* emb = (const float*)d_in[0];
    const float* wt = (const float*)d_in[1];
    const float* bias = (const float*)d_in[2];
    const int* labels = (const int*)d_in[3];

    const int B = 2, S = 2048;
    const int V = in_sizes[2];            // 50257
    const int NR = B * S;                 // 4096
    const int NVT = (V + BN - 1) / BN;    // 197
    const int Vpad = NVT * BN;            // 50432

    char* p = (char*)d_ws;
    unsigned short* E16 = (unsigned short*)p;
    p += (size_t)NR * DD * 2;
    float2* partials = (float2*)p;
    p += (size_t)NR * NVT * sizeof(float2);
    float* tl = (float*)p;
    p += (size_t)NR * 4;
    int* validf = (int*)p;
    p += (size_t)NR * 4;
    float* accum = (float*)p;
    p += 256;
    unsigned short* W16 = (unsigned short*)p;

    hipMemsetAsync(accum, 0, 8, stream);

    size_t echunks = (size_t)NR * DD / 8;
    convE_k<<<(int)((echunks + 255) / 256), 256, 0, stream>>>(emb, E16, echunks);

    size_t wchunks = (size_t)Vpad * DD / 8;
    convW_k<<<8192, 256, 0, stream>>>(wt, W16, V, wchunks);

    hipFuncSetAttribute((const void*)gemm_lse256_k,
                        hipFuncAttributeMaxDynamicSharedMemorySize, LDS_TOTAL);
    gemm_lse256_k<<<NMT * NVT, THREADS, LDS_TOTAL, stream>>>(E16, W16, bias,
                                                             partials, NVT, V);

    true_logit_k<<<NR / 4, 256, 0, stream>>>(emb, wt, bias, labels, tl, validf,
                                             NR, V, S);
    reduce_rows_k<<<NR / 4, 256, 0, stream>>>(partials, tl, validf, accum, NR,
                                              NVT, S);
    finalize_k<<<1, 1, 0, stream>>>(accum, (float*)d_out);
}

// Round 3
// 1010.740 us; speedup vs baseline: 1.2194x; 1.0109x over previous
//
#include <hip/hip_runtime.h>

#define IGNORE_INDEX (-100)
#define DD 2048
#define BM 256
#define BN 256
#define BK 64
#define NKT 32   // DD/BK
#define NMT 16   // 4096/BM
#define THREADS 512
#define LDS_TOTAL 139264

typedef __attribute__((ext_vector_type(8))) short bf16x8;
typedef __attribute__((ext_vector_type(4))) float f32x4;

__device__ __forceinline__ unsigned short f2bf(float f) {
    union { float f; unsigned u; } x; x.f = f;
    unsigned r = x.u + 0x7FFFu + ((x.u >> 16) & 1u);
    return (unsigned short)(r >> 16);
}

__device__ __forceinline__ void gload_lds16(const void* g, void* l) {
    __builtin_amdgcn_global_load_lds(
        (const __attribute__((address_space(1))) void*)g,
        (__attribute__((address_space(3))) void*)l, 16, 0, 0);
}

// ---------------- fp32 -> bf16 conversion (embeddings) --------------------
__global__ __launch_bounds__(256) void convE_k(const float* __restrict__ in,
                                               unsigned short* __restrict__ out,
                                               size_t nchunks) {
    size_t i = (size_t)blockIdx.x * 256 + threadIdx.x;
    if (i >= nchunks) return;
    const float4* src = (const float4*)(in + i * 8);
    float4 a = src[0], b = src[1];
    ushort4 o0 = { f2bf(a.x), f2bf(a.y), f2bf(a.z), f2bf(a.w) };
    ushort4 o1 = { f2bf(b.x), f2bf(b.y), f2bf(b.z), f2bf(b.w) };
    ushort4* dst = (ushort4*)(out + i * 8);
    dst[0] = o0; dst[1] = o1;
}

// ---------------- fp32 -> bf16 conversion (weight, zero-pad to Vpad) ------
__global__ __launch_bounds__(256) void convW_k(const float* __restrict__ wt,
                                               unsigned short* __restrict__ out,
                                               int V, size_t nchunks) {
    for (size_t i = (size_t)blockIdx.x * 256 + threadIdx.x; i < nchunks;
         i += (size_t)gridDim.x * 256) {
        size_t base = i * 8;
        size_t v = base >> 11;  // / DD
        ushort4 o0 = {0, 0, 0, 0}, o1 = {0, 0, 0, 0};
        if (v < (size_t)V) {
            const float4* src = (const float4*)(wt + base);
            float4 a = *(const float4*)&src[0];
            float4 b = *(const float4*)&src[1];
            o0 = (ushort4){ f2bf(a.x), f2bf(a.y), f2bf(a.z), f2bf(a.w) };
            o1 = (ushort4){ f2bf(b.x), f2bf(b.y), f2bf(b.z), f2bf(b.w) };
        }
        ushort4* dst = (ushort4*)(out + base);
        dst[0] = o0; dst[1] = o1;
    }
}

// ---------------- 256x256 8-phase GEMM + online-LSE epilogue --------------
// LDS map (dynamic): bufA0 @0 (32K), bufB0 @32768, bufA1 @65536, bufB1 @98304,
//                    redM @131072 (4K), redS @135168 (4K). Total 139264.
// Swizzle (T2): lds byte for (row R, col-byte cb) = R*128 + (cb ^ ((R&7)<<4));
// R&7 == lo&7 (A/B reads) == srow (stage) -> XOR term is fragment-invariant,
// hoisted into 8 precomputed base offsets; fragment selection is a
// compile-time immediate (folds into ds_read offset field).
// Stage slot ledger (phases 0..7 of iter i; buf0=T(2i), buf1=T(2i+1)):
//   ph0: T(2i+1).A0 -> buf1.A   ph1: T(2i+1).A1
//   ph2: T(2i+2).B0 -> buf0.B   ph3: T(2i+2).B1 + vmcnt(4)
//   ph4: T(2i+2).A0 -> buf0.A   ph5: T(2i+2).A1
//   ph6: T(2i+3).B0 -> buf1.B   ph7: T(2i+3).B1 + vmcnt(4)
// vmcnt(4) at ph3 drains T(2i+1).A (+ prev-iter B leftovers), leaving only
// the 4 loads issued at ph2/ph3 in flight. Symmetric at ph7. Sinking a stage
// below its WAITV only makes the wait stricter (monotone-safe); hoisting is
// blocked by the asm "memory" clobber.

#define LDA4(B, MH)                                                         \
    do {                                                                    \
        _Pragma("unroll") for (int mm = 0; mm < 4; ++mm)                    \
        _Pragma("unroll") for (int kk = 0; kk < 2; ++kk)                    \
            a[mm][kk] = ldA(B, MH, mm, kk);                                 \
    } while (0)
#define LDB4(B, NH, ARR)                                                    \
    do {                                                                    \
        _Pragma("unroll") for (int nn = 0; nn < 2; ++nn)                    \
        _Pragma("unroll") for (int kk = 0; kk < 2; ++kk)                    \
            ARR[nn][kk] = ldB(B, NH, nn, kk);                               \
    } while (0)
// barrier -> MFMA cluster -> barrier -> single sched fence (prevents next
// phase's LDS ops hoisting above the barrier; allows compile-time interleave
// of this phase's VALU/loads with the MFMA region).
#define PHASE_MFMA(MH, NH, ARR)                                             \
    do {                                                                    \
        __builtin_amdgcn_s_barrier();                                       \
        __builtin_amdgcn_s_setprio(1);                                      \
        _Pragma("unroll") for (int mm = 0; mm < 4; ++mm)                    \
        _Pragma("unroll") for (int nn = 0; nn < 2; ++nn)                    \
        _Pragma("unroll") for (int kk = 0; kk < 2; ++kk)                    \
            acc[(MH)*4 + mm][(NH)*2 + nn] =                                 \
                __builtin_amdgcn_mfma_f32_16x16x32_bf16(                    \
                    a[mm][kk], ARR[nn][kk], acc[(MH)*4 + mm][(NH)*2 + nn],  \
                    0, 0, 0);                                               \
        __builtin_amdgcn_s_setprio(0);                                      \
        __builtin_amdgcn_s_barrier();                                       \
        __builtin_amdgcn_sched_barrier(0);                                  \
    } while (0)
#define WAITV(N) asm volatile("s_waitcnt vmcnt(" #N ")" ::: "memory")

__global__ __launch_bounds__(THREADS, 2) void gemm_lse256_k(
    const unsigned short* __restrict__ E16,   // [4096][DD] bf16 bits
    const unsigned short* __restrict__ W16,   // [Vpad][DD] bf16 bits
    const float* __restrict__ bias,           // [V]
    float2* __restrict__ partials,            // [NR][NVT]
    int NVT, int V) {
    extern __shared__ char smem[];
    const int t = threadIdx.x;
    const int lane = t & 63;
    const int wave = t >> 6;
    const int wr = wave >> 2;   // 0..1
    const int wc = wave & 3;    // 0..3
    const int lo = lane & 15;
    const int hi = lane >> 4;

    // bijective XCD swizzle (m204)
    const int nwg = NMT * NVT;
    const int xcd = blockIdx.x & 7;
    const int idx = blockIdx.x >> 3;
    const int q8 = nwg >> 3, r8 = nwg & 7;
    const int swz = (xcd < r8 ? xcd * (q8 + 1) : r8 * (q8 + 1) + (xcd - r8) * q8) + idx;
    const int mt = swz & (NMT - 1);
    const int vt = swz >> 4;

    const unsigned short* Ag = E16 + (size_t)mt * BM * DD;
    const unsigned short* Bg = W16 + (size_t)vt * BN * DD;

    f32x4 acc[8][4];
#pragma unroll
    for (int m = 0; m < 8; ++m)
#pragma unroll
        for (int n = 0; n < 4; ++n) acc[m][n] = (f32x4){0.f, 0.f, 0.f, 0.f};
    bf16x8 a[4][2], b0[2][2], b1[2][2];

    // ---- precomputed LDS read base offsets (loop-invariant) ----
    const int xorm = (lo & 7) << 4;
    int cbx[2];
    cbx[0] = (hi * 16) ^ xorm;
    cbx[1] = (64 + hi * 16) ^ xorm;
    int offA[2][2], offB[2][2];  // [buf][kk] byte offsets into smem
#pragma unroll
    for (int b = 0; b < 2; ++b)
#pragma unroll
        for (int k = 0; k < 2; ++k) {
            offA[b][k] = b * 65536 + (wr * 128 + lo) * 128 + cbx[k];
            offB[b][k] = 32768 + b * 65536 + (wc * 64 + lo) * 128 + cbx[k];
        }
    auto ldA = [&](int b, int mh, int mm, int kk) -> bf16x8 {
        return *(const bf16x8*)(smem + offA[b][kk] + mh * 8192 + mm * 2048);
    };
    auto ldB = [&](int b, int nh, int nn, int kk) -> bf16x8 {
        return *(const bf16x8*)(smem + offB[b][kk] + nh * 4096 + nn * 2048);
    };

    // ---- precomputed stage pointers (loop-invariant) ----
    const int srow = lane >> 3;
    const int cbs = ((lane & 7) * 16) ^ (srow << 4);
    const unsigned short* gA[2][2];  // [j][h]
    const unsigned short* gB[2][2];
#pragma unroll
    for (int j = 0; j < 2; ++j)
#pragma unroll
        for (int h = 0; h < 2; ++h) {
            int row = (wave * 2 + j) * 8 + srow;
            gA[j][h] = Ag + (size_t)(h * 128 + row) * DD + (cbs >> 1);
            gB[j][h] = Bg + (size_t)(h * 128 + row) * DD + (cbs >> 1);
        }
    const int wbyte = wave * 2048;  // dest: smem + b*65536 + (A?0:32768) + h*16384 + wbyte + j*1024

    auto stageA = [&](int b, int h, int kt) {
        int ktc = (kt & (NKT - 1)) * BK;
#pragma unroll
        for (int j = 0; j < 2; ++j)
            gload_lds16(gA[j][h] + ktc,
                        smem + b * 65536 + h * 16384 + wbyte + j * 1024);
    };
    auto stageB = [&](int b, int h, int kt) {
        int ktc = (kt & (NKT - 1)) * BK;
#pragma unroll
        for (int j = 0; j < 2; ++j)
            gload_lds16(gB[j][h] + ktc,
                        smem + 32768 + b * 65536 + h * 16384 + wbyte + j * 1024);
    };

    // prologue: T0 (all 4 halves) -> buf0; T1.B0,B1 -> buf1
    stageA(0, 0, 0); stageA(0, 1, 0);
    stageB(0, 0, 0); stageB(0, 1, 0);
    stageB(1, 0, 1); stageB(1, 1, 1);
    WAITV(4);   // T0 fully landed; T1.B0,B1 in flight
    __builtin_amdgcn_s_barrier();
    __builtin_amdgcn_sched_barrier(0);

    for (int i = 0; i < NKT / 2; ++i) {
        const int k0 = 2 * i;
        // ph0
        LDA4(0, 0); LDB4(0, 0, b0);
        stageA(1, 0, k0 + 1);
        PHASE_MFMA(0, 0, b0);
        // ph1
        LDB4(0, 1, b1);
        stageA(1, 1, k0 + 1);
        PHASE_MFMA(0, 1, b1);
        // ph2
        LDA4(0, 1);
        stageB(0, 0, k0 + 2);
        PHASE_MFMA(1, 1, b1);
        // ph3
        stageB(0, 1, k0 + 2);
        WAITV(4);
        PHASE_MFMA(1, 0, b0);
        // ph4
        LDA4(1, 0); LDB4(1, 0, b0);
        stageA(0, 0, k0 + 2);
        PHASE_MFMA(0, 0, b0);
        // ph5
        LDB4(1, 1, b1);
        stageA(0, 1, k0 + 2);
        PHASE_MFMA(0, 1, b1);
        // ph6
        LDA4(1, 1);
        stageB(1, 0, k0 + 3);
        PHASE_MFMA(1, 1, b1);
        // ph7
        stageB(1, 1, k0 + 3);
        WAITV(4);
        PHASE_MFMA(1, 0, b0);
    }

    WAITV(0);
    __syncthreads();

    // ---- epilogue: bias add + per-row (max, sumexp) over this 256-col tile
    float* redM = (float*)(smem + 131072);
    float* redS = (float*)(smem + 135168);
    const int colbase = vt * BN + wc * 64 + lo;
    float bias_n[4];
#pragma unroll
    for (int n = 0; n < 4; ++n) {
        int col = colbase + n * 16;
        bias_n[n] = (col < V) ? bias[col] : 0.0f;
    }
#pragma unroll
    for (int m = 0; m < 8; ++m) {
#pragma unroll
        for (int qq = 0; qq < 4; ++qq) {
            float l[4];
            float vmax = -1e30f;
#pragma unroll
            for (int n = 0; n < 4; ++n) {
                int col = colbase + n * 16;
                float x = (col < V) ? (acc[m][n][qq] + bias_n[n]) : -1e30f;
                l[n] = x;
                vmax = fmaxf(vmax, x);
            }
#pragma unroll
            for (int d = 1; d < 16; d <<= 1) vmax = fmaxf(vmax, __shfl_xor(vmax, d));
            float s = 0.f;
#pragma unroll
            for (int n = 0; n < 4; ++n) s += __expf(l[n] - vmax);
#pragma unroll
            for (int d = 1; d < 16; d <<= 1) s += __shfl_xor(s, d);
            if (lo == 0) {
                int R = wr * 128 + m * 16 + hi * 4 + qq;
                redM[wc * 256 + R] = vmax;
                redS[wc * 256 + R] = s;
            }
        }
    }
    __syncthreads();
    if (t < 256) {
        float M = redM[t], S = redS[t];
#pragma unroll
        for (int w2 = 1; w2 < 4; ++w2) {
            float m2 = redM[w2 * 256 + t], s2 = redS[w2 * 256 + t];
            float nM = fmaxf(M, m2);
            S = S * __expf(M - nM) + s2 * __expf(m2 - nM);
            M = nM;
        }
        size_t row = (size_t)mt * BM + t;
        partials[row * (size_t)NVT + vt] = make_float2(M, S);
    }
}

// ---------------- fp32 true-logit per row (one wave per row) --------------
__global__ __launch_bounds__(256) void true_logit_k(
    const float* __restrict__ emb, const float* __restrict__ wt,
    const float* __restrict__ bias, const int* __restrict__ labels,
    float* __restrict__ tl, int* __restrict__ validf, int NR, int V, int S) {
    int wid = blockIdx.x * 4 + (threadIdx.x >> 6);
    int lane = threadIdx.x & 63;
    if (wid >= NR) return;
    int b = wid / S, s = wid % S;
    int valid = 0;
    float val = 0.f;
    if (s < S - 1) {
        int y = labels[b * S + s + 1];
        if (y != IGNORE_INDEX) {
            valid = 1;
            int ys = (y >= 0 && y < V) ? y : 0;
            const float4* e4 = (const float4*)(emb + ((size_t)b * S + s) * DD);
            const float4* w4 = (const float4*)(wt + (size_t)ys * DD);
            float sum = 0.f;
            for (int i = lane; i < DD / 4; i += 64) {
                float4 aa = e4[i], w = w4[i];
                sum += aa.x * w.x + aa.y * w.y + aa.z * w.z + aa.w * w.w;
            }
#pragma unroll
            for (int d = 1; d < 64; d <<= 1) sum += __shfl_xor(sum, d);
            val = sum + bias[ys];
        }
    }
    if (lane == 0) {
        tl[wid] = val;
        validf[wid] = valid;
    }
}

// ---------------- combine partials -> per-row NLL -> global sum -----------
__global__ __launch_bounds__(256) void reduce_rows_k(
    const float2* __restrict__ partials, const float* __restrict__ tl,
    const int* __restrict__ validf, float* __restrict__ accum, int NR,
    int NVT, int S) {
    int wid = blockIdx.x * 4 + (threadIdx.x >> 6);
    int lane = threadIdx.x & 63;
    if (wid >= NR) return;
    int s = wid % S;
    if (s >= S - 1) return;
    if (!validf[wid]) return;
    float M = -1e30f, Sm = 0.f;
    const float2* p = partials + (size_t)wid * NVT;
    for (int v = lane; v < NVT; v += 64) {
        float2 ms = p[v];
        float nM = fmaxf(M, ms.x);
        Sm = Sm * __expf(M - nM) + ms.y * __expf(ms.x - nM);
        M = nM;
    }
#pragma unroll
    for (int d = 1; d < 64; d <<= 1) {
        float oM = __shfl_xor(M, d), oS = __shfl_xor(Sm, d);
        float nM = fmaxf(M, oM);
        Sm = Sm * __expf(M - nM) + oS * __expf(oM - nM);
        M = nM;
    }
    if (lane == 0) {
        float lse = M + __logf(Sm);
        float nll = lse - tl[wid];
        atomicAdd(&accum[0], nll);
        atomicAdd(&accum[1], 1.0f);
    }
}

__global__ void finalize_k(const float* __restrict__ accum,
                           float* __restrict__ out) {
    out[0] = accum[0] / fmaxf(accum[1], 1.0f);
}

extern "C" void kernel_launch(void* const* d_in, const int* in_sizes, int n_in,
                              void* d_out, int out_size, void* d_ws,
                              size_t ws_size, hipStream_t stream) {
    const float* emb = (const float*)d_in[0];
    const float* wt = (const float*)d_in[1];
    const float* bias = (const float*)d_in[2];
    const int* labels = (const int*)d_in[3];

    const int B = 2, S = 2048;
    const int V = in_sizes[2];            // 50257
    const int NR = B * S;                 // 4096
    const int NVT = (V + BN - 1) / BN;    // 197
    const int Vpad = NVT * BN;            // 50432

    char* p = (char*)d_ws;
    unsigned short* E16 = (unsigned short*)p;
    p += (size_t)NR * DD * 2;
    float2* partials = (float2*)p;
    p += (size_t)NR * NVT * sizeof(float2);
    float* tl = (float*)p;
    p += (size_t)NR * 4;
    int* validf = (int*)p;
    p += (size_t)NR * 4;
    float* accum = (float*)p;
    p += 256;
    unsigned short* W16 = (unsigned short*)p;

    hipMemsetAsync(accum, 0, 8, stream);

    size_t echunks = (size_t)NR * DD / 8;
    convE_k<<<(int)((echunks + 255) / 256), 256, 0, stream>>>(emb, E16, echunks);

    size_t wchunks = (size_t)Vpad * DD / 8;
    convW_k<<<8192, 256, 0, stream>>>(wt, W16, V, wchunks);

    hipFuncSetAttribute((const void*)gemm_lse256_k,
                        hipFuncAttributeMaxDynamicSharedMemorySize, LDS_TOTAL);
    gemm_lse256_k<<<NMT * NVT, THREADS, LDS_TOTAL, stream>>>(E16, W16, bias,
                                                             partials, NVT, V);

    true_logit_k<<<NR / 4, 256, 0, stream>>>(emb, wt, bias, labels, tl, validf,
                                             NR, V, S);
    reduce_rows_k<<<NR / 4, 256, 0, stream>>>(partials, tl, validf, accum, NR,
                                              NVT, S);
    finalize_k<<<1, 1, 0, stream>>>(accum, (float*)d_out);
}

// Round 4
// 978.032 us; speedup vs baseline: 1.2602x; 1.0334x over previous
//
#include <hip/hip_runtime.h>

#define IGNORE_INDEX (-100)
#define DD 2048
#define BM 256
#define BN 256
#define BK 64
#define NKT 32   // DD/BK
#define NMT 16   // 4096/BM
#define THREADS 512
#define LDS_TOTAL 139264

typedef __attribute__((ext_vector_type(8))) short bf16x8;
typedef __attribute__((ext_vector_type(4))) float f32x4;

__device__ __forceinline__ unsigned short f2bf(float f) {
    union { float f; unsigned u; } x; x.f = f;
    unsigned r = x.u + 0x7FFFu + ((x.u >> 16) & 1u);
    return (unsigned short)(r >> 16);
}

__device__ __forceinline__ void gload_lds16(const void* g, void* l) {
    __builtin_amdgcn_global_load_lds(
        (const __attribute__((address_space(1))) void*)g,
        (__attribute__((address_space(3))) void*)l, 16, 0, 0);
}

// ---------------- fp32 -> bf16 conversion (embeddings) --------------------
__global__ __launch_bounds__(256) void convE_k(const float* __restrict__ in,
                                               unsigned short* __restrict__ out,
                                               size_t nchunks) {
    size_t i = (size_t)blockIdx.x * 256 + threadIdx.x;
    if (i >= nchunks) return;
    const float4* src = (const float4*)(in + i * 8);
    float4 a = src[0], b = src[1];
    ushort4 o0 = { f2bf(a.x), f2bf(a.y), f2bf(a.z), f2bf(a.w) };
    ushort4 o1 = { f2bf(b.x), f2bf(b.y), f2bf(b.z), f2bf(b.w) };
    ushort4* dst = (ushort4*)(out + i * 8);
    dst[0] = o0; dst[1] = o1;
}

// ---------------- fp32 -> bf16 conversion (weight, zero-pad to Vpad) ------
__global__ __launch_bounds__(256) void convW_k(const float* __restrict__ wt,
                                               unsigned short* __restrict__ out,
                                               int V, size_t nchunks) {
    for (size_t i = (size_t)blockIdx.x * 256 + threadIdx.x; i < nchunks;
         i += (size_t)gridDim.x * 256) {
        size_t base = i * 8;
        size_t v = base >> 11;  // / DD
        ushort4 o0 = {0, 0, 0, 0}, o1 = {0, 0, 0, 0};
        if (v < (size_t)V) {
            const float4* src = (const float4*)(wt + base);
            float4 a = *(const float4*)&src[0];
            float4 b = *(const float4*)&src[1];
            o0 = (ushort4){ f2bf(a.x), f2bf(a.y), f2bf(a.z), f2bf(a.w) };
            o1 = (ushort4){ f2bf(b.x), f2bf(b.y), f2bf(b.z), f2bf(b.w) };
        }
        ushort4* dst = (ushort4*)(out + base);
        dst[0] = o0; dst[1] = o1;
    }
}

// ---------------- 256x256 pipelined GEMM + online-LSE epilogue ------------
// ONE barrier per region; region = {MFMA on fragments read in the PREVIOUS
// region | ds_reads for the NEXT region | 1 half-tile stage issue}.
//
// LDS map: bufA0 @0, bufB0 @32768, bufA1 @65536, bufB1 @98304 (32K each),
//          redM @131072, redS @135168. Swizzle: byte = R*128 + (cb^((R&7)<<4)).
//
// Steady-state ledger (iter i; buf0=T(2i), buf1=T(2i+1)); per wave 2
// gload_lds per region:
//  region | MFMA (uses regs from) | reads (for next)        | stage          | waitv
//  R0     | (0,0) aX,bP  [R7']    | c1  <- buf0.B nh1       | buf1.A.h0 2i+1 |
//  R1     | (0,1) aX,c1  [R0]     | aY  <- buf0.A mh1       | buf1.A.h1 2i+1 |
//  R2     | (1,1) aY,c1  [R1,R0]  | --                      | buf0.B.h0 2i+2 | W(2)
//  R3     | (1,0) aY,bP           | aX<-buf1.A mh0, bQ<-buf1.B nh0 | buf0.B.h1 2i+2 |
//  R4     | (0,0) aX,bQ  [R3]     | c1  <- buf1.B nh1       | buf0.A.h0 2i+2 |
//  R5     | (0,1) aX,c1  [R4]     | aY  <- buf1.A mh1       | buf0.A.h1 2i+2 |
//  R6     | (1,1) aY,c1  [R5,R4]  | --                      | buf1.B.h0 2i+3 | W(2)
//  R7     | (1,0) aY,bQ           | aX<-buf0.A mh0, bP<-buf0.B nh0 | buf1.B.h1 2i+3 |
// WAITV(2)@R2-end: outstanding 10 -> 2: drains buf1.B (prev R6/R7) + buf1.A
//   (R0/R1) BEFORE the R2/R3 barrier -> publishes all waves' buf1 stages for
//   R3/R5's reads. WAITV(2)@R6-end: drains buf0.B (R2/R3) + buf0.A (R4/R5)
//   for R7's reads. Leaves exactly 2 in flight each time (this region's).
// Write-after-read: every stage's target buffer had its last read-ISSUE >=2
//   regions earlier, consumed by MFMA >=1 region earlier, published by this
//   region's pre-barrier. Reads vs same-region stages: disjoint buffers (all
//   8 regions checked). sched_barrier(0) after each s_barrier pins DS/VMEM
//   ops to their region (s_barrier alone is not a compiler memory fence).

#define LDA8(DST, B, MH)                                                    \
    do {                                                                    \
        _Pragma("unroll") for (int mm = 0; mm < 4; ++mm)                    \
        _Pragma("unroll") for (int kk = 0; kk < 2; ++kk)                    \
            DST[mm][kk] = *(const bf16x8*)(smem + offA[B][kk] +             \
                                           (MH)*8192 + mm * 2048);          \
    } while (0)
#define LDB4(DST, B, NH)                                                    \
    do {                                                                    \
        _Pragma("unroll") for (int nn = 0; nn < 2; ++nn)                    \
        _Pragma("unroll") for (int kk = 0; kk < 2; ++kk)                    \
            DST[nn][kk] = *(const bf16x8*)(smem + offB[B][kk] +             \
                                           (NH)*4096 + nn * 2048);          \
    } while (0)
#define MFMAQ(MH, NH, AARR, BARR)                                           \
    do {                                                                    \
        __builtin_amdgcn_s_setprio(1);                                      \
        _Pragma("unroll") for (int mm = 0; mm < 4; ++mm)                    \
        _Pragma("unroll") for (int nn = 0; nn < 2; ++nn)                    \
        _Pragma("unroll") for (int kk = 0; kk < 2; ++kk)                    \
            acc[(MH)*4 + mm][(NH)*2 + nn] =                                 \
                __builtin_amdgcn_mfma_f32_16x16x32_bf16(                    \
                    AARR[mm][kk], BARR[nn][kk],                             \
                    acc[(MH)*4 + mm][(NH)*2 + nn], 0, 0, 0);                \
        __builtin_amdgcn_s_setprio(0);                                      \
    } while (0)
#define RBAR()                                                              \
    do {                                                                    \
        __builtin_amdgcn_s_barrier();                                       \
        __builtin_amdgcn_sched_barrier(0);                                  \
    } while (0)
#define WAITV(N) asm volatile("s_waitcnt vmcnt(" #N ")" ::: "memory")

__global__ __launch_bounds__(THREADS, 2) void gemm_lse256_k(
    const unsigned short* __restrict__ E16,   // [4096][DD] bf16 bits
    const unsigned short* __restrict__ W16,   // [Vpad][DD] bf16 bits
    const float* __restrict__ bias,           // [V]
    float2* __restrict__ partials,            // [NR][NVT]
    int NVT, int V) {
    extern __shared__ char smem[];
    const int t = threadIdx.x;
    const int lane = t & 63;
    const int wave = t >> 6;
    const int wr = wave >> 2;   // 0..1
    const int wc = wave & 3;    // 0..3
    const int lo = lane & 15;
    const int hi = lane >> 4;

    // bijective XCD swizzle (m204)
    const int nwg = NMT * NVT;
    const int xcd = blockIdx.x & 7;
    const int idx = blockIdx.x >> 3;
    const int q8 = nwg >> 3, r8 = nwg & 7;
    const int swz = (xcd < r8 ? xcd * (q8 + 1) : r8 * (q8 + 1) + (xcd - r8) * q8) + idx;
    const int mt = swz & (NMT - 1);
    const int vt = swz >> 4;

    const unsigned short* Ag = E16 + (size_t)mt * BM * DD;
    const unsigned short* Bg = W16 + (size_t)vt * BN * DD;

    f32x4 acc[8][4];
#pragma unroll
    for (int m = 0; m < 8; ++m)
#pragma unroll
        for (int n = 0; n < 4; ++n) acc[m][n] = (f32x4){0.f, 0.f, 0.f, 0.f};
    bf16x8 aX[4][2], aY[4][2], bP[2][2], bQ[2][2], c1[2][2];

    // ---- precomputed LDS read base offsets (loop-invariant) ----
    const int xorm = (lo & 7) << 4;
    int cbx[2];
    cbx[0] = (hi * 16) ^ xorm;
    cbx[1] = (64 + hi * 16) ^ xorm;
    int offA[2][2], offB[2][2];  // [buf][kk] byte offsets into smem
#pragma unroll
    for (int b = 0; b < 2; ++b)
#pragma unroll
        for (int k = 0; k < 2; ++k) {
            offA[b][k] = b * 65536 + (wr * 128 + lo) * 128 + cbx[k];
            offB[b][k] = 32768 + b * 65536 + (wc * 64 + lo) * 128 + cbx[k];
        }

    // ---- precomputed stage pointers (loop-invariant) ----
    const int srow = lane >> 3;
    const int cbs = ((lane & 7) * 16) ^ (srow << 4);
    const unsigned short* gA[2][2];  // [j][h]
    const unsigned short* gB[2][2];
#pragma unroll
    for (int j = 0; j < 2; ++j)
#pragma unroll
        for (int h = 0; h < 2; ++h) {
            int row = (wave * 2 + j) * 8 + srow;
            gA[j][h] = Ag + (size_t)(h * 128 + row) * DD + (cbs >> 1);
            gB[j][h] = Bg + (size_t)(h * 128 + row) * DD + (cbs >> 1);
        }
    const int wbyte = wave * 2048;

    auto stageA = [&](int b, int h, int kt) {
        int ktc = (kt & (NKT - 1)) * BK;
#pragma unroll
        for (int j = 0; j < 2; ++j)
            gload_lds16(gA[j][h] + ktc,
                        smem + b * 65536 + h * 16384 + wbyte + j * 1024);
    };
    auto stageB = [&](int b, int h, int kt) {
        int ktc = (kt & (NKT - 1)) * BK;
#pragma unroll
        for (int j = 0; j < 2; ++j)
            gload_lds16(gB[j][h] + ktc,
                        smem + 32768 + b * 65536 + h * 16384 + wbyte + j * 1024);
    };

    // prologue: T0 -> buf0 (4 halves), T1.B -> buf1 (2 halves)
    stageA(0, 0, 0); stageA(0, 1, 0);
    stageB(0, 0, 0); stageB(0, 1, 0);
    stageB(1, 0, 1); stageB(1, 1, 1);
    WAITV(4);   // T0 landed; T1.B (4 loads) in flight
    __builtin_amdgcn_s_barrier();
    __builtin_amdgcn_sched_barrier(0);
    // pre-load R0's operands from buf0
    LDA8(aX, 0, 0);
    LDB4(bP, 0, 0);

    for (int i = 0; i < NKT / 2; ++i) {
        const int k1 = 2 * i + 1, k2 = 2 * i + 2, k3 = 2 * i + 3;
        // R0
        RBAR();
        MFMAQ(0, 0, aX, bP);
        LDB4(c1, 0, 1);
        stageA(1, 0, k1);
        // R1
        RBAR();
        MFMAQ(0, 1, aX, c1);
        LDA8(aY, 0, 1);
        stageA(1, 1, k1);
        // R2
        RBAR();
        MFMAQ(1, 1, aY, c1);
        stageB(0, 0, k2);
        WAITV(2);
        // R3
        RBAR();
        MFMAQ(1, 0, aY, bP);
        LDA8(aX, 1, 0);
        LDB4(bQ, 1, 0);
        stageB(0, 1, k2);
        // R4
        RBAR();
        MFMAQ(0, 0, aX, bQ);
        LDB4(c1, 1, 1);
        stageA(0, 0, k2);
        // R5
        RBAR();
        MFMAQ(0, 1, aX, c1);
        LDA8(aY, 1, 1);
        stageA(0, 1, k2);
        // R6
        RBAR();
        MFMAQ(1, 1, aY, c1);
        stageB(1, 0, k3);
        WAITV(2);
        // R7
        RBAR();
        MFMAQ(1, 0, aY, bQ);
        LDA8(aX, 0, 0);
        LDB4(bP, 0, 0);
        stageB(1, 1, k3);
    }

    WAITV(0);
    __syncthreads();

    // ---- epilogue: bias add + per-row (max, sumexp) over this 256-col tile
    float* redM = (float*)(smem + 131072);
    float* redS = (float*)(smem + 135168);
    const int colbase = vt * BN + wc * 64 + lo;
    float bias_n[4];
#pragma unroll
    for (int n = 0; n < 4; ++n) {
        int col = colbase + n * 16;
        bias_n[n] = (col < V) ? bias[col] : 0.0f;
    }
#pragma unroll
    for (int m = 0; m < 8; ++m) {
#pragma unroll
        for (int qq = 0; qq < 4; ++qq) {
            float l[4];
            float vmax = -1e30f;
#pragma unroll
            for (int n = 0; n < 4; ++n) {
                int col = colbase + n * 16;
                float x = (col < V) ? (acc[m][n][qq] + bias_n[n]) : -1e30f;
                l[n] = x;
                vmax = fmaxf(vmax, x);
            }
#pragma unroll
            for (int d = 1; d < 16; d <<= 1) vmax = fmaxf(vmax, __shfl_xor(vmax, d));
            float s = 0.f;
#pragma unroll
            for (int n = 0; n < 4; ++n) s += __expf(l[n] - vmax);
#pragma unroll
            for (int d = 1; d < 16; d <<= 1) s += __shfl_xor(s, d);
            if (lo == 0) {
                int R = wr * 128 + m * 16 + hi * 4 + qq;
                redM[wc * 256 + R] = vmax;
                redS[wc * 256 + R] = s;
            }
        }
    }
    __syncthreads();
    if (t < 256) {
        float M = redM[t], S = redS[t];
#pragma unroll
        for (int w2 = 1; w2 < 4; ++w2) {
            float m2 = redM[w2 * 256 + t], s2 = redS[w2 * 256 + t];
            float nM = fmaxf(M, m2);
            S = S * __expf(M - nM) + s2 * __expf(m2 - nM);
            M = nM;
        }
        size_t row = (size_t)mt * BM + t;
        partials[row * (size_t)NVT + vt] = make_float2(M, S);
    }
}

// ---------------- fp32 true-logit per row (one wave per row) --------------
__global__ __launch_bounds__(256) void true_logit_k(
    const float* __restrict__ emb, const float* __restrict__ wt,
    const float* __restrict__ bias, const int* __restrict__ labels,
    float* __restrict__ tl, int* __restrict__ validf, int NR, int V, int S) {
    int wid = blockIdx.x * 4 + (threadIdx.x >> 6);
    int lane = threadIdx.x & 63;
    if (wid >= NR) return;
    int b = wid / S, s = wid % S;
    int valid = 0;
    float val = 0.f;
    if (s < S - 1) {
        int y = labels[b * S + s + 1];
        if (y != IGNORE_INDEX) {
            valid = 1;
            int ys = (y >= 0 && y < V) ? y : 0;
            const float4* e4 = (const float4*)(emb + ((size_t)b * S + s) * DD);
            const float4* w4 = (const float4*)(wt + (size_t)ys * DD);
            float sum = 0.f;
            for (int i = lane; i < DD / 4; i += 64) {
                float4 aa = e4[i], w = w4[i];
                sum += aa.x * w.x + aa.y * w.y + aa.z * w.z + aa.w * w.w;
            }
#pragma unroll
            for (int d = 1; d < 64; d <<= 1) sum += __shfl_xor(sum, d);
            val = sum + bias[ys];
        }
    }
    if (lane == 0) {
        tl[wid] = val;
        validf[wid] = valid;
    }
}

// ---------------- combine partials -> per-row NLL -> global sum -----------
__global__ __launch_bounds__(256) void reduce_rows_k(
    const float2* __restrict__ partials, const float* __restrict__ tl,
    const int* __restrict__ validf, float* __restrict__ accum, int NR,
    int NVT, int S) {
    int wid = blockIdx.x * 4 + (threadIdx.x >> 6);
    int lane = threadIdx.x & 63;
    if (wid >= NR) return;
    int s = wid % S;
    if (s >= S - 1) return;
    if (!validf[wid]) return;
    float M = -1e30f, Sm = 0.f;
    const float2* p = partials + (size_t)wid * NVT;
    for (int v = lane; v < NVT; v += 64) {
        float2 ms = p[v];
        float nM = fmaxf(M, ms.x);
        Sm = Sm * __expf(M - nM) + ms.y * __expf(ms.x - nM);
        M = nM;
    }
#pragma unroll
    for (int d = 1; d < 64; d <<= 1) {
        float oM = __shfl_xor(M, d), oS = __shfl_xor(Sm, d);
        float nM = fmaxf(M, oM);
        Sm = Sm * __expf(M - nM) + oS * __expf(oM - nM);
        M = nM;
    }
    if (lane == 0) {
        float lse = M + __logf(Sm);
        float nll = lse - tl[wid];
        atomicAdd(&accum[0], nll);
        atomicAdd(&accum[1], 1.0f);
    }
}

__global__ void finalize_k(const float* __restrict__ accum,
                           float* __restrict__ out) {
    out[0] = accum[0] / fmaxf(accum[1], 1.0f);
}

extern "C" void kernel_launch(void* const* d_in, const int* in_sizes, int n_in,
                              void* d_out, int out_size, void* d_ws,
                              size_t ws_size, hipStream_t stream) {
    const float* emb = (const float*)d_in[0];
    const float* wt = (const float*)d_in[1];
    const float* bias = (const float*)d_in[2];
    const int* labels = (const int*)d_in[3];

    const int B = 2, S = 2048;
    const int V = in_sizes[2];            // 50257
    const int NR = B * S;                 // 4096
    const int NVT = (V + BN - 1) / BN;    // 197
    const int Vpad = NVT * BN;            // 50432

    char* p = (char*)d_ws;
    unsigned short* E16 = (unsigned short*)p;
    p += (size_t)NR * DD * 2;
    float2* partials = (float2*)p;
    p += (size_t)NR * NVT * sizeof(float2);
    float* tl = (float*)p;
    p += (size_t)NR * 4;
    int* validf = (int*)p;
    p += (size_t)NR * 4;
    float* accum = (float*)p;
    p += 256;
    unsigned short* W16 = (unsigned short*)p;

    hipMemsetAsync(accum, 0, 8, stream);

    size_t echunks = (size_t)NR * DD / 8;
    convE_k<<<(int)((echunks + 255) / 256), 256, 0, stream>>>(emb, E16, echunks);

    size_t wchunks = (size_t)Vpad * DD / 8;
    convW_k<<<8192, 256, 0, stream>>>(wt, W16, V, wchunks);

    hipFuncSetAttribute((const void*)gemm_lse256_k,
                        hipFuncAttributeMaxDynamicSharedMemorySize, LDS_TOTAL);
    gemm_lse256_k<<<NMT * NVT, THREADS, LDS_TOTAL, stream>>>(E16, W16, bias,
                                                             partials, NVT, V);

    true_logit_k<<<NR / 4, 256, 0, stream>>>(emb, wt, bias, labels, tl, validf,
                                             NR, V, S);
    reduce_rows_k<<<NR / 4, 256, 0, stream>>>(partials, tl, validf, accum, NR,
                                              NVT, S);
    finalize_k<<<1, 1, 0, stream>>>(accum, (float*)d_out);
}